// Round 7
// baseline (202.898 us; speedup 1.0000x reference)
//
#include <hip/hip_runtime.h>

typedef _Float16 half8 __attribute__((ext_vector_type(8)));
typedef _Float16 half4v __attribute__((ext_vector_type(4)));
typedef _Float16 half2v __attribute__((ext_vector_type(2)));
typedef float f32x4 __attribute__((ext_vector_type(4)));

// async 16B global->LDS copy (HW: LDS dest = wave-uniform base + lane*16)
#define ASYNC_CP16(gp, lp)                                       \
  __builtin_amdgcn_global_load_lds(                              \
      (const __attribute__((address_space(1))) void*)(gp),       \
      (__attribute__((address_space(3))) void*)(lp), 16, 0, 0)

static __device__ __forceinline__ half8 mulw(half8 a, half8 s) {
  half8 o;
#pragma unroll
  for (int j = 0; j < 8; j++) o[j] = a[j] * s[j];  // v_pk_mul_f16 x4
  return o;
}

// ---------------------------------------------------------------------------
// Convert Wq||Wk||Wv (fp32 [O,512] each) -> Wb fp16 [1024][512] (c-inner)
// ---------------------------------------------------------------------------
__global__ __launch_bounds__(256) void conv_w(const float* __restrict__ Wq,
                                              const float* __restrict__ Wk,
                                              const float* __restrict__ Wv,
                                              _Float16* __restrict__ Wb) {
  int idx = blockIdx.x * 256 + threadIdx.x;  // 0 .. 1024*512
  int row = idx >> 9;
  float v;
  if (row < 256)      v = Wq[idx];
  else if (row < 512) v = Wk[idx - 256 * 512];
  else                v = Wv[idx - 512 * 512];
  Wb[idx] = (_Float16)v;
}

// ---------------------------------------------------------------------------
// x fp32 [B][512][2048] -> xT fp16 [B][2048][512]   (LDS-tiled transpose)
// ---------------------------------------------------------------------------
__global__ __launch_bounds__(256) void conv_xT(const float* __restrict__ x,
                                               _Float16* __restrict__ xT) {
  __shared__ float T[32][33];
  const int b = blockIdx.z;
  const int n0 = blockIdx.x * 32, c0 = blockIdx.y * 32;
  const int t = threadIdx.x;
  const float* xb = x + (size_t)b * 512 * 2048;
  const int n2 = t & 15, cr = t >> 4;  // load: 16 float2-cols x 16 c-rows
#pragma unroll
  for (int r = 0; r < 2; r++) {
    int c = cr + r * 16;
    float2 v = *(const float2*)&xb[(size_t)(c0 + c) * 2048 + n0 + n2 * 2];
    T[c][n2 * 2] = v.x;
    T[c][n2 * 2 + 1] = v.y;
  }
  __syncthreads();
  _Float16* xtb = xT + (size_t)b * 2048 * 512;
  const int c2 = t & 15, nr = t >> 4;  // store: 16 half2-cols x 16 n-rows
#pragma unroll
  for (int r = 0; r < 2; r++) {
    int n = nr + r * 16;
    half2v h;
    h[0] = (_Float16)T[c2 * 2][n];
    h[1] = (_Float16)T[c2 * 2 + 1][n];
    *(half2v*)&xtb[(size_t)(n0 + n) * 512 + c0 + c2 * 2] = h;
  }
}

// ---------------------------------------------------------------------------
// NT-GEMM (proj + sim), ROUND-7: phase-split schedule (R6-proven on gemm_av:
// 63.5->47us, MfmaUtil 19.5->27).  C[m][n] = sum_k A[m][k]*B[n][k], fp16.
// Block 512 thr = 8 waves (2m x 4c), tile 128m x 256n, wave 64x64 (4x4).
// BK=64 as 2 kk sub-phases; 3 LDS bufs, prefetch dist 2 K-tiles; staging
// all cp16 (6/thread/tile: 2 A + 4 B) issued in phase 0; ONE counted
// vmcnt(6) per tile at the phase-1 wait (retires stage T+1, keeps stage
// T+2 in flight across barriers; drained only at the tail).
// Per phase: {ds_read kk frags -> issue stage -> barrier -> setprio 16 MFMA
// setprio -> barrier}.  sched_barrier(0) after each asm barrier (rule #18).
// XOR swizzle on the GLOBAL source side (sigma(row)=(row>>1)&3, invariant
// under row+128) keeps frag ds_read_b128 conflict-free - proven R0/R6.
// LDS 144 KB (As 3x2x8KB + Bs 3x2x16KB) -> 1 block/CU, 2 waves/SIMD =
// gemm_av R6's proven occupancy quadrant.
// MODE 1 (PROJ3): m_blk<512 -> transposed fp16 store into C (qkT); else
//   natural fp16 store into C2 (v) at row m-512.  (m_blk<512 block-uniform)
// MODE 2 (SIM): store h = fp16(exp(logit - mx)), mx = per-wave column max
//   over its 64 m's; partials pm/ps at 64-row group (m_blk+wm)>>6 =
//   blockIdx.y*2 + (wave&1); each (group, n) written by exactly one wave
//   (waves differ in wn).  NT: 8 (proj, K=512) / 4 (sim, K=256).
// ---------------------------------------------------------------------------
#define STAGE_NT(bb, kbase)                                   \
  ASYNC_CP16(gA + (kbase), &As[bb][0][wofs]);                 \
  ASYNC_CP16(gA + (kbase) + 32, &As[bb][1][wofs]);            \
  ASYNC_CP16(gB + (kbase), &Bs[bb][0][wofs]);                 \
  ASYNC_CP16(gB2 + (kbase), &Bs[bb][0][4096 + wofs]);         \
  ASYNC_CP16(gB + (kbase) + 32, &Bs[bb][1][wofs]);            \
  ASYNC_CP16(gB2 + (kbase) + 32, &Bs[bb][1][4096 + wofs]);

template <int MODE, int NT>
__global__ __launch_bounds__(512) void gemm_nt(
    const _Float16* __restrict__ A, const _Float16* __restrict__ B,
    _Float16* __restrict__ C, _Float16* __restrict__ C2, int lda, int ldb,
    int ldc, int ldc2, long sA, long sB, long sC, float* __restrict__ pm,
    float* __restrict__ ps) {
  A += (size_t)blockIdx.z * sA;
  B += (size_t)blockIdx.z * sB;
  C += (size_t)blockIdx.z * sC;
  if constexpr (MODE == 1) C2 += (size_t)blockIdx.z * sC;
  const int m_blk = blockIdx.y * 128, n_blk = blockIdx.x * 256;

  __shared__ __align__(16) _Float16 As[3][2][4096];  // [buf][kk][128r x 32k]
  __shared__ __align__(16) _Float16 Bs[3][2][8192];  // [buf][kk][256r x 32k]

  const int t = threadIdx.x;
  const int lane = t & 63, wave = t >> 6;
  const int quad = lane >> 4, l16 = lane & 15;
  const int wm = (wave & 1) * 64, wn = (wave >> 1) * 64;

  // staging: thread t -> row t>>2, slot t&3, swizzled data chunk
  const int arow = t >> 2, aslot = t & 3;
  const int adc = aslot ^ ((arow >> 1) & 3);  // global-side XOR swizzle
  const _Float16* gA = A + (size_t)(m_blk + arow) * lda + adc * 8;
  const _Float16* gB = B + (size_t)(n_blk + arow) * ldb + adc * 8;
  const _Float16* gB2 = gB + (size_t)128 * ldb;  // sigma invariant (+128)
  const int wofs = wave * 512 + lane * 8;  // wave-uniform base + lane*16B

  const int rchunk = (quad ^ ((l16 >> 1) & 3)) * 8;

  f32x4 acc[4][4] = {};

  // ---- prologue: stage tiles 0,1 (6 cp16 each) ----
  STAGE_NT(0, 0);
  STAGE_NT(1, 64);
  asm volatile("s_waitcnt vmcnt(6)\n\ts_barrier" ::: "memory");
  __builtin_amdgcn_sched_barrier(0);

  int cbuf = 0;
  for (int T = 0; T < NT; T++) {
    const int kb2 = (T + 2) * 64;
    // ---------------- phase 0 (kk0) ----------------
    half8 af[4], bf[4];
#pragma unroll
    for (int i = 0; i < 4; i++) {
      af[i] = *(const half8*)&As[cbuf][0][(wm + i * 16 + l16) * 32 + rchunk];
      bf[i] = *(const half8*)&Bs[cbuf][0][(wn + i * 16 + l16) * 32 + rchunk];
    }
    if (T + 2 < NT) {  // stage T+2 (oldest-first vmcnt bookkeeping)
      int nb = cbuf + 2;
      if (nb >= 3) nb -= 3;
      STAGE_NT(nb, kb2);
    }
    asm volatile("s_barrier" ::: "memory");
    __builtin_amdgcn_sched_barrier(0);
    __builtin_amdgcn_s_setprio(1);
#pragma unroll
    for (int i = 0; i < 4; i++)
#pragma unroll
      for (int j = 0; j < 4; j++)
        acc[i][j] =
            __builtin_amdgcn_mfma_f32_16x16x32_f16(af[i], bf[j], acc[i][j], 0, 0, 0);
    __builtin_amdgcn_s_setprio(0);
    asm volatile("s_barrier" ::: "memory");
    __builtin_amdgcn_sched_barrier(0);
    // ---------------- phase 1 (kk1) ----------------
    half8 af2[4], bf2[4];
#pragma unroll
    for (int i = 0; i < 4; i++) {
      af2[i] = *(const half8*)&As[cbuf][1][(wm + i * 16 + l16) * 32 + rchunk];
      bf2[i] = *(const half8*)&Bs[cbuf][1][(wn + i * 16 + l16) * 32 + rchunk];
    }
    if (T + 2 < NT)  // retire stage T+1, keep stage T+2 in flight
      asm volatile("s_waitcnt vmcnt(6)\n\ts_barrier" ::: "memory");
    else
      asm volatile("s_waitcnt vmcnt(0)\n\ts_barrier" ::: "memory");
    __builtin_amdgcn_sched_barrier(0);
    __builtin_amdgcn_s_setprio(1);
#pragma unroll
    for (int i = 0; i < 4; i++)
#pragma unroll
      for (int j = 0; j < 4; j++)
        acc[i][j] =
            __builtin_amdgcn_mfma_f32_16x16x32_f16(af2[i], bf2[j], acc[i][j], 0, 0, 0);
    __builtin_amdgcn_s_setprio(0);
    asm volatile("s_barrier" ::: "memory");
    __builtin_amdgcn_sched_barrier(0);
    cbuf++;
    if (cbuf == 3) cbuf = 0;
  }

  if constexpr (MODE == 2) {
    // per-wave-column softmax partials + exp-store (D row = quad*4+reg,
    // col = l16 in each 16x16 tile; wave column has 64 m's across i,quad,r)
#pragma unroll
    for (int j = 0; j < 4; j++) {
      const int n0 = n_blk + wn + j * 16 + l16;
      float mx = acc[0][j][0];
#pragma unroll
      for (int i = 0; i < 4; i++)
#pragma unroll
        for (int r = 0; r < 4; r++) mx = fmaxf(mx, acc[i][j][r]);
      mx = fmaxf(mx, __shfl_xor(mx, 16, 64));
      mx = fmaxf(mx, __shfl_xor(mx, 32, 64));
      float es = 0.f;
#pragma unroll
      for (int i = 0; i < 4; i++) {
        const int m0 = m_blk + wm + i * 16 + quad * 4;
#pragma unroll
        for (int r = 0; r < 4; r++) {
          _Float16 h = (_Float16)__expf(acc[i][j][r] - mx);
          C[(size_t)(m0 + r) * ldc + n0] = h;
          es += (float)h;
        }
      }
      es += __shfl_xor(es, 16, 64);
      es += __shfl_xor(es, 32, 64);
      if (quad == 0) {
        size_t o = ((size_t)blockIdx.z * 32 + blockIdx.y * 2 + (wave & 1)) *
                       2048 + n0;
        pm[o] = mx;
        ps[o] = es;
      }
    }
  } else {
#pragma unroll
    for (int i = 0; i < 4; i++) {
      const int m0 = m_blk + wm + i * 16 + quad * 4;
#pragma unroll
      for (int j = 0; j < 4; j++) {
        const int n0 = n_blk + wn + j * 16 + l16;
        if (m_blk < 512) {  // q|k rows: transposed store into qkT
          half4v h;
#pragma unroll
          for (int r = 0; r < 4; r++) h[r] = (_Float16)acc[i][j][r];
          *(half4v*)&C[(size_t)n0 * ldc + m0] = h;
        } else {  // v rows: natural store v[(m-512)][n]
#pragma unroll
          for (int r = 0; r < 4; r++)
            C2[(size_t)(m0 - 512 + r) * ldc2 + n0] = (_Float16)acc[i][j][r];
        }
      }
    }
  }
}

// ---------------------------------------------------------------------------
// Merge 32 per-64-row partials per column -> fp16 scale[b][32][2048]:
// scale[i][col] = exp(pm_i - M) / S,  S = sum_i ps_i * exp(pm_i - M).
// attn[m,k] = h[m,k] * scale[m>>6, k]; normalization exact by construction.
// Grid (nb*2048/256).
// ---------------------------------------------------------------------------
__global__ __launch_bounds__(256) void colstats2(const float* __restrict__ pm,
                                                 const float* __restrict__ ps,
                                                 _Float16* __restrict__ scl) {
  const int idx = blockIdx.x * 256 + threadIdx.x;  // b*2048 + col
  const int b = idx >> 11, col = idx & 2047;
  const float* pmb = pm + (size_t)b * 32 * 2048 + col;
  const float* psb = ps + (size_t)b * 32 * 2048 + col;
  float pv[32];
  float m = -3.0e38f;
#pragma unroll
  for (int i = 0; i < 32; i++) {
    pv[i] = pmb[(size_t)i * 2048];
    m = fmaxf(m, pv[i]);
  }
  float s = 0.f;
#pragma unroll
  for (int i = 0; i < 32; i++) {
    pv[i] = __expf(pv[i] - m);
    s += psb[(size_t)i * 2048] * pv[i];
  }
  const float inv = 1.0f / s;
  _Float16* so = scl + (size_t)b * 32 * 2048 + col;
#pragma unroll
  for (int i = 0; i < 32; i++) so[(size_t)i * 2048] = (_Float16)(pv[i] * inv);
}

// ---------------------------------------------------------------------------
// Stage-D: out[m][c] = sum_k (P[m][k]*scale[m>>6,k]) * V[c][k].
// P fp16 [2048][2048] (unnorm. exp), V fp16 [512][2048], scale fp16 [32][2048]
// per batch, out fp32 [2048][512].
// ROUND-6 (PROVEN, unchanged): phase-split schedule (T3+T4+T5 port).
// 512 thr, tile 128m x 256c, wave 64x64 (4x4), grid 32/batch x 8 = 256 =
// 1 block/CU, batch-per-XCD.  BK64 as 2 sub-phases; B via 4 cp16 issued in
// ph0; A reg+mulw(scale)+ds_write, glob prefetch dist 2 issued in ph1;
// counted vmcnt(4) once per K-tile.  Measured: 47us, MfmaUtil 27.
// ---------------------------------------------------------------------------
__global__ __launch_bounds__(512) void gemm_av(const _Float16* __restrict__ P,
                                               const _Float16* __restrict__ V,
                                               const _Float16* __restrict__ scl,
                                               float* __restrict__ C,
                                               int cbatch) {
  int lin = blockIdx.x, z, idx;
  if (cbatch == 8) {
    z = lin & 7;      // batch = XCD
    idx = lin >> 3;   // 0..31
  } else {
    z = lin >> 5;
    idx = lin & 31;
  }
  const int n_blk = (idx & 1) * 256;   // c-dim (2 blocks)
  const int m_blk = (idx >> 1) * 128;  // m-dim (16 blocks)
  P += (size_t)z * 2048 * 2048;
  V += (size_t)z * 512 * 2048;
  scl += (size_t)z * 32 * 2048;
  C += (size_t)z * 2048 * 512;

  __shared__ __align__(16) _Float16 Asv[2][2][4096];  // [buf][kk][128r x 32k]
  __shared__ __align__(16) _Float16 Bsv[2][2][8192];  // [buf][kk][256r x 32k]

  const int t = threadIdx.x;
  const int lane = t & 63, wave = t >> 6;
  const int quad = lane >> 4, l16 = lane & 15;
  const int wm = (wave & 1) * 64, wn = (wave >> 1) * 64;

  // A staging: thread t -> row t>>2, slot chunk t&3, swizzled data chunk
  const int arow = t >> 2;                       // 0..127
  const int aslot = t & 3;
  const int adc = aslot ^ ((arow >> 1) & 3);     // global-side XOR swizzle
  const _Float16* gA = P + (size_t)(m_blk + arow) * 2048 + adc * 8;
  const _Float16* gS = scl + (size_t)((m_blk + arow) >> 6) * 2048 + adc * 8;
  const int awofs = arow * 32 + aslot * 8;

  // B staging (cp16): per wave-instruction 16 rows x 64 B; sigma(row) is
  // rhalf-invariant ((r>>1)&3 with r = rhalf*128 + brow0, 128/2 % 4 == 0)
  const int brow0 = (wave << 4) + (lane >> 2);          // 0..127
  const int bdc = (lane & 3) ^ ((brow0 >> 1) & 3);
  const _Float16* gB = V + (size_t)(n_blk + brow0) * 2048 + bdc * 8;
  const int bwofs = wave << 9;  // wave*512 halves (HW adds lane*16B)

  const int rchunk = (quad ^ ((l16 >> 1) & 3)) * 8;

  f32x4 acc[4][4] = {};

  // ---- prologue: B tile0 (4 cp16); A tile0 staged; A tile1 in regs ----
  ASYNC_CP16(gB, &Bsv[0][0][bwofs]);
  ASYNC_CP16(gB + (size_t)128 * 2048, &Bsv[0][0][4096 + bwofs]);
  ASYNC_CP16(gB + 32, &Bsv[0][1][bwofs]);
  ASYNC_CP16(gB + (size_t)128 * 2048 + 32, &Bsv[0][1][4096 + bwofs]);
  {
    half8 a00 = *(const half8*)(gA);
    half8 s00 = *(const half8*)(gS);
    half8 a01 = *(const half8*)(gA + 32);
    half8 s01 = *(const half8*)(gS + 32);
    *(half8*)&Asv[0][0][awofs] = mulw(a00, s00);
    *(half8*)&Asv[0][1][awofs] = mulw(a01, s01);
  }
  half8 pA0 = *(const half8*)(gA + 64);
  half8 pS0 = *(const half8*)(gS + 64);
  half8 pA1 = *(const half8*)(gA + 96);
  half8 pS1 = *(const half8*)(gS + 96);
  asm volatile("s_waitcnt vmcnt(4) lgkmcnt(0)\n\ts_barrier" ::: "memory");
  __builtin_amdgcn_sched_barrier(0);

  for (int T = 0; T < 32; T++) {
    const int c = T & 1, n = c ^ 1;
    const int k1 = (T + 1) * 64;  // B stage k-base
    const int k2 = (T + 2) * 64;  // A glob prefetch k-base
    // ---------------- phase 0 ----------------
    half8 af[4], bf[4];
#pragma unroll
    for (int i = 0; i < 4; i++) {
      af[i] = *(const half8*)&Asv[c][0][(wm + i * 16 + l16) * 32 + rchunk];
      bf[i] = *(const half8*)&Bsv[c][0][(wn + i * 16 + l16) * 32 + rchunk];
    }
    if (T < 31) {  // all 4 B cp16 (oldest in vmcnt queue) + A kk0 write
      ASYNC_CP16(gB + k1, &Bsv[n][0][bwofs]);
      ASYNC_CP16(gB + (size_t)128 * 2048 + k1, &Bsv[n][0][4096 + bwofs]);
      ASYNC_CP16(gB + k1 + 32, &Bsv[n][1][bwofs]);
      ASYNC_CP16(gB + (size_t)128 * 2048 + k1 + 32, &Bsv[n][1][4096 + bwofs]);
      *(half8*)&Asv[n][0][awofs] = mulw(pA0, pS0);
    }
    asm volatile("s_barrier" ::: "memory");
    __builtin_amdgcn_sched_barrier(0);
    __builtin_amdgcn_s_setprio(1);
#pragma unroll
    for (int i = 0; i < 4; i++)
#pragma unroll
      for (int j = 0; j < 4; j++)
        acc[i][j] =
            __builtin_amdgcn_mfma_f32_16x16x32_f16(af[i], bf[j], acc[i][j], 0, 0, 0);
    __builtin_amdgcn_s_setprio(0);
    asm volatile("s_barrier" ::: "memory");
    __builtin_amdgcn_sched_barrier(0);
    // ---------------- phase 1 ----------------
    half8 af2[4], bf2[4];
#pragma unroll
    for (int i = 0; i < 4; i++) {
      af2[i] = *(const half8*)&Asv[c][1][(wm + i * 16 + l16) * 32 + rchunk];
      bf2[i] = *(const half8*)&Bsv[c][1][(wn + i * 16 + l16) * 32 + rchunk];
    }
    half8 fA0, fS0, fA1, fS1;
    if (T < 30) {  // A glob prefetch for T+2 (stays in flight across barrier)
      fA0 = *(const half8*)(gA + k2);
      fS0 = *(const half8*)(gS + k2);
      fA1 = *(const half8*)(gA + k2 + 32);
      fS1 = *(const half8*)(gS + k2 + 32);
    }
    if (T < 31) *(half8*)&Asv[n][1][awofs] = mulw(pA1, pS1);
    if (T < 30) {
      pA0 = fA0;
      pS0 = fS0;
      pA1 = fA1;
      pS1 = fS1;
    }
    if (T < 30)
      asm volatile("s_waitcnt vmcnt(4) lgkmcnt(0)\n\ts_barrier" ::: "memory");
    else
      asm volatile("s_waitcnt vmcnt(0) lgkmcnt(0)\n\ts_barrier" ::: "memory");
    __builtin_amdgcn_sched_barrier(0);
    __builtin_amdgcn_s_setprio(1);
#pragma unroll
    for (int i = 0; i < 4; i++)
#pragma unroll
      for (int j = 0; j < 4; j++)
        acc[i][j] =
            __builtin_amdgcn_mfma_f32_16x16x32_f16(af2[i], bf2[j], acc[i][j], 0, 0, 0);
    __builtin_amdgcn_s_setprio(0);
    asm volatile("s_barrier" ::: "memory");
    __builtin_amdgcn_sched_barrier(0);
  }

  // epilogue: natural fp32 store C[m][c]
#pragma unroll
  for (int i = 0; i < 4; i++) {
    const int m0 = m_blk + wm + i * 16 + quad * 4;
#pragma unroll
    for (int j = 0; j < 4; j++) {
      const int n0 = n_blk + wn + j * 16 + l16;
#pragma unroll
      for (int r = 0; r < 4; r++) C[(size_t)(m0 + r) * 512 + n0] = acc[i][j][r];
    }
  }
}

// ---------------------------------------------------------------------------
extern "C" void kernel_launch(void* const* d_in, const int* in_sizes, int n_in,
                              void* d_out, int out_size, void* d_ws,
                              size_t ws_size, hipStream_t stream) {
  const float* x = (const float*)d_in[0];
  const float* Wq = (const float*)d_in[1];
  const float* Wk = (const float*)d_in[2];
  const float* Wv = (const float*)d_in[3];
  float* out = (float*)d_out;

  char* p = (char*)d_ws;
  auto alloc = [&](size_t bytes) -> char* {
    char* r = p;
    p += (bytes + 255) & ~(size_t)255;
    return r;
  };
  const size_t NB = 8, N = 2048, CIN = 512, CO = 512;
  _Float16* Wb = (_Float16*)alloc(1024 * 512 * sizeof(_Float16));
  _Float16* xT = (_Float16*)alloc(NB * N * CIN * sizeof(_Float16));
  _Float16* qkT = (_Float16*)alloc(NB * N * 512 * sizeof(_Float16));  // [n][q|k]
  _Float16* v = (_Float16*)alloc(NB * CO * N * sizeof(_Float16));     // [c][n]
  size_t base_used = (size_t)(p - (char*)d_ws);

  // per-batch bytes for the sim chain: fp16 P + partials + scale + slack
  const size_t per_b =
      (size_t)N * N * 2 + 2 * 32 * N * 4 + 32 * N * 2 + 8192;
  int cb = 8;
  while (cb > 1 && base_used + (size_t)cb * per_b > ws_size) cb >>= 1;
  _Float16* simH = (_Float16*)alloc((size_t)cb * N * N * 2);
  float* pm = (float*)alloc((size_t)cb * 32 * N * 4);
  float* ps = (float*)alloc((size_t)cb * 32 * N * 4);
  _Float16* scl = (_Float16*)alloc((size_t)cb * 32 * N * 2);

  // 1) weight convert + x transpose-convert
  conv_w<<<dim3(1024 * 512 / 256), 256, 0, stream>>>(Wq, Wk, Wv, Wb);
  conv_xT<<<dim3(64, 16, 8), 256, 0, stream>>>(x, xT);

  // 2) merged projections (q,k,v in one pass over xT), phase-split:
  //    rows<512 -> qkT[n][o] transposed; rows>=512 -> v[c][n] natural
  gemm_nt<1, 8><<<dim3(8, 8, 8), 512, 0, stream>>>(
      Wb, xT, qkT, v, 512, 512, 512, 2048, 0, (long)(N * CIN),
      (long)(N * 512), nullptr, nullptr);

  // 3) per-chunk: simH = fp16(exp(qT.kT^T - mx_wave)) + partials; merge ->
  //    fp16 scale; stage-D GEMM applies scale during A-staging -> out
  for (int b0 = 0; b0 < 8; b0 += cb) {
    const _Float16* qT = qkT + (size_t)b0 * N * 512;        // [m][c], lda 512
    const _Float16* kT = qkT + (size_t)b0 * N * 512 + 256;  // [k][c], ldb 512
    gemm_nt<2, 4><<<dim3(8, 16, cb), 512, 0, stream>>>(
        qT, kT, simH, nullptr, 512, 512, 2048, 0, (long)(N * 512),
        (long)(N * 512), (long)(N * N), pm, ps);
    colstats2<<<dim3(cb * 8), 256, 0, stream>>>(pm, ps, scl);
    gemm_av<<<dim3(32 * cb), 512, 0, stream>>>(
        simH, v + (size_t)b0 * CO * N, scl, out + (size_t)b0 * N * CO, cb);
  }
}

// Round 8
// 195.875 us; speedup vs baseline: 1.0359x; 1.0359x over previous
//
#include <hip/hip_runtime.h>

typedef _Float16 half8 __attribute__((ext_vector_type(8)));
typedef _Float16 half4v __attribute__((ext_vector_type(4)));
typedef _Float16 half2v __attribute__((ext_vector_type(2)));
typedef float f32x4 __attribute__((ext_vector_type(4)));

// async 16B global->LDS copy (HW: LDS dest = wave-uniform base + lane*16)
#define ASYNC_CP16(gp, lp)                                       \
  __builtin_amdgcn_global_load_lds(                              \
      (const __attribute__((address_space(1))) void*)(gp),       \
      (__attribute__((address_space(3))) void*)(lp), 16, 0, 0)

static __device__ __forceinline__ half8 mulw(half8 a, half8 s) {
  half8 o;
#pragma unroll
  for (int j = 0; j < 8; j++) o[j] = a[j] * s[j];  // v_pk_mul_f16 x4
  return o;
}

// ---------------------------------------------------------------------------
// Convert Wq||Wk||Wv (fp32 [O,512] each) -> Wb fp16 [1024][512] (c-inner)
// ---------------------------------------------------------------------------
__global__ __launch_bounds__(256) void conv_w(const float* __restrict__ Wq,
                                              const float* __restrict__ Wk,
                                              const float* __restrict__ Wv,
                                              _Float16* __restrict__ Wb) {
  int idx = blockIdx.x * 256 + threadIdx.x;  // 0 .. 1024*512
  int row = idx >> 9;
  float v;
  if (row < 256)      v = Wq[idx];
  else if (row < 512) v = Wk[idx - 256 * 512];
  else                v = Wv[idx - 512 * 512];
  Wb[idx] = (_Float16)v;
}

// ---------------------------------------------------------------------------
// x fp32 [B][512][2048] -> xT fp16 [B][2048][512]   (LDS-tiled transpose)
// ---------------------------------------------------------------------------
__global__ __launch_bounds__(256) void conv_xT(const float* __restrict__ x,
                                               _Float16* __restrict__ xT) {
  __shared__ float T[32][33];
  const int b = blockIdx.z;
  const int n0 = blockIdx.x * 32, c0 = blockIdx.y * 32;
  const int t = threadIdx.x;
  const float* xb = x + (size_t)b * 512 * 2048;
  const int n2 = t & 15, cr = t >> 4;  // load: 16 float2-cols x 16 c-rows
#pragma unroll
  for (int r = 0; r < 2; r++) {
    int c = cr + r * 16;
    float2 v = *(const float2*)&xb[(size_t)(c0 + c) * 2048 + n0 + n2 * 2];
    T[c][n2 * 2] = v.x;
    T[c][n2 * 2 + 1] = v.y;
  }
  __syncthreads();
  _Float16* xtb = xT + (size_t)b * 2048 * 512;
  const int c2 = t & 15, nr = t >> 4;  // store: 16 half2-cols x 16 n-rows
#pragma unroll
  for (int r = 0; r < 2; r++) {
    int n = nr + r * 16;
    half2v h;
    h[0] = (_Float16)T[c2 * 2][n];
    h[1] = (_Float16)T[c2 * 2 + 1][n];
    *(half2v*)&xtb[(size_t)(n0 + n) * 512 + c0 + c2 * 2] = h;
  }
}

// ---------------------------------------------------------------------------
// NT-GEMM proj (R7-proven phase-split; used ONLY for MODE 1 / NT 8 now).
// Block 512 thr = 8 waves (2m x 4c), tile 128m x 256n, wave 64x64 (4x4).
// BK=64 as 2 kk sub-phases; 3 LDS bufs, prefetch dist 2 K-tiles; staging
// all cp16 (6/thread/tile) in phase 0; ONE counted vmcnt(6) per tile.
// ---------------------------------------------------------------------------
#define STAGE_NT(bb, kbase)                                   \
  ASYNC_CP16(gA + (kbase), &As[bb][0][wofs]);                 \
  ASYNC_CP16(gA + (kbase) + 32, &As[bb][1][wofs]);            \
  ASYNC_CP16(gB + (kbase), &Bs[bb][0][wofs]);                 \
  ASYNC_CP16(gB2 + (kbase), &Bs[bb][0][4096 + wofs]);         \
  ASYNC_CP16(gB + (kbase) + 32, &Bs[bb][1][wofs]);            \
  ASYNC_CP16(gB2 + (kbase) + 32, &Bs[bb][1][4096 + wofs]);

template <int NT>
__global__ __launch_bounds__(512) void gemm_proj(
    const _Float16* __restrict__ A, const _Float16* __restrict__ B,
    _Float16* __restrict__ C, _Float16* __restrict__ C2, int lda, int ldb,
    int ldc, int ldc2, long sA, long sB, long sC) {
  A += (size_t)blockIdx.z * sA;
  B += (size_t)blockIdx.z * sB;
  C += (size_t)blockIdx.z * sC;
  C2 += (size_t)blockIdx.z * sC;
  const int m_blk = blockIdx.y * 128, n_blk = blockIdx.x * 256;

  __shared__ __align__(16) _Float16 As[3][2][4096];  // [buf][kk][128r x 32k]
  __shared__ __align__(16) _Float16 Bs[3][2][8192];  // [buf][kk][256r x 32k]

  const int t = threadIdx.x;
  const int lane = t & 63, wave = t >> 6;
  const int quad = lane >> 4, l16 = lane & 15;
  const int wm = (wave & 1) * 64, wn = (wave >> 1) * 64;

  const int arow = t >> 2, aslot = t & 3;
  const int adc = aslot ^ ((arow >> 1) & 3);  // global-side XOR swizzle
  const _Float16* gA = A + (size_t)(m_blk + arow) * lda + adc * 8;
  const _Float16* gB = B + (size_t)(n_blk + arow) * ldb + adc * 8;
  const _Float16* gB2 = gB + (size_t)128 * ldb;  // sigma invariant (+128)
  const int wofs = wave * 512 + lane * 8;

  const int rchunk = (quad ^ ((l16 >> 1) & 3)) * 8;

  f32x4 acc[4][4] = {};

  STAGE_NT(0, 0);
  STAGE_NT(1, 64);
  asm volatile("s_waitcnt vmcnt(6)\n\ts_barrier" ::: "memory");
  __builtin_amdgcn_sched_barrier(0);

  int cbuf = 0;
  for (int T = 0; T < NT; T++) {
    const int kb2 = (T + 2) * 64;
    // ---------------- phase 0 (kk0) ----------------
    half8 af[4], bf[4];
#pragma unroll
    for (int i = 0; i < 4; i++) {
      af[i] = *(const half8*)&As[cbuf][0][(wm + i * 16 + l16) * 32 + rchunk];
      bf[i] = *(const half8*)&Bs[cbuf][0][(wn + i * 16 + l16) * 32 + rchunk];
    }
    if (T + 2 < NT) {
      int nb = cbuf + 2;
      if (nb >= 3) nb -= 3;
      STAGE_NT(nb, kb2);
    }
    asm volatile("s_barrier" ::: "memory");
    __builtin_amdgcn_sched_barrier(0);
    __builtin_amdgcn_s_setprio(1);
#pragma unroll
    for (int i = 0; i < 4; i++)
#pragma unroll
      for (int j = 0; j < 4; j++)
        acc[i][j] =
            __builtin_amdgcn_mfma_f32_16x16x32_f16(af[i], bf[j], acc[i][j], 0, 0, 0);
    __builtin_amdgcn_s_setprio(0);
    asm volatile("s_barrier" ::: "memory");
    __builtin_amdgcn_sched_barrier(0);
    // ---------------- phase 1 (kk1) ----------------
    half8 af2[4], bf2[4];
#pragma unroll
    for (int i = 0; i < 4; i++) {
      af2[i] = *(const half8*)&As[cbuf][1][(wm + i * 16 + l16) * 32 + rchunk];
      bf2[i] = *(const half8*)&Bs[cbuf][1][(wn + i * 16 + l16) * 32 + rchunk];
    }
    if (T + 2 < NT)
      asm volatile("s_waitcnt vmcnt(6)\n\ts_barrier" ::: "memory");
    else
      asm volatile("s_waitcnt vmcnt(0)\n\ts_barrier" ::: "memory");
    __builtin_amdgcn_sched_barrier(0);
    __builtin_amdgcn_s_setprio(1);
#pragma unroll
    for (int i = 0; i < 4; i++)
#pragma unroll
      for (int j = 0; j < 4; j++)
        acc[i][j] =
            __builtin_amdgcn_mfma_f32_16x16x32_f16(af2[i], bf2[j], acc[i][j], 0, 0, 0);
    __builtin_amdgcn_s_setprio(0);
    asm volatile("s_barrier" ::: "memory");
    __builtin_amdgcn_sched_barrier(0);
    cbuf++;
    if (cbuf == 3) cbuf = 0;
  }

  // epilogue (PROJ): m_blk<512 -> transposed fp16 store (qkT); else v natural
#pragma unroll
  for (int i = 0; i < 4; i++) {
    const int m0 = m_blk + wm + i * 16 + quad * 4;
#pragma unroll
    for (int j = 0; j < 4; j++) {
      const int n0 = n_blk + wn + j * 16 + l16;
      if (m_blk < 512) {
        half4v h;
#pragma unroll
        for (int r = 0; r < 4; r++) h[r] = (_Float16)acc[i][j][r];
        *(half4v*)&C[(size_t)n0 * ldc + m0] = h;
      } else {
#pragma unroll
        for (int r = 0; r < 4; r++)
          C2[(size_t)(m0 - 512 + r) * ldc2 + n0] = (_Float16)acc[i][j][r];
      }
    }
  }
}

// ---------------------------------------------------------------------------
// SIM kernel, ROUND-8: back to the occupancy regime.  R7's 512-thr/144KB
// phase-split port REGRESSED sim (47->55us, Occ 19%): K=256 -> only 4
// K-tiles, pipeline mostly prologue/tail, and 1 block/CU means the heavy
// epilogue (64 expf + scattered stores/thread) can't overlap other blocks.
// Fix: R0-PROVEN 256-thr / 128x128 / BUFS=3 2-phase loop (exact code path
// proven as R0's proj): LDS 48KB -> 3 blocks/CU, counted vmcnt(4) mid-loop
// (retires tile T+1 only, keeps T+2 in flight; drains only at tail).
// K=256, lda=ldb=512, ldc=2048 hardcoded.
// Epilogue: h = fp16(exp(logit-mx)), mx = per-wave column max over its 64
// m's; partials pm/ps per 64-row group (blockIdx.y*2 + (wave&1)).
// ---------------------------------------------------------------------------
__global__ __launch_bounds__(256) void gemm_sim(
    const _Float16* __restrict__ A, const _Float16* __restrict__ B,
    _Float16* __restrict__ C, long sA, long sB, long sC,
    float* __restrict__ pm, float* __restrict__ ps) {
  A += (size_t)blockIdx.z * sA;
  B += (size_t)blockIdx.z * sB;
  C += (size_t)blockIdx.z * sC;
  const int m_blk = blockIdx.y * 128, n_blk = blockIdx.x * 128;

  __shared__ __align__(16) _Float16 As[3][4096];  // [buf][128 rows][32 k]
  __shared__ __align__(16) _Float16 Bs[3][4096];

  const int t = threadIdx.x;
  const int lane = t & 63, wave = t >> 6;
  const int quad = lane >> 4, l16 = lane & 15;
  const int wm = (wave & 1) * 64, wn = (wave >> 1) * 64;

  const int srow = 16 * wave + (lane >> 2);
  const int schunk = (lane & 3) ^ ((lane >> 3) & 3);  // XOR swizzle
  const _Float16* gA0 = A + (size_t)(m_blk + srow) * 512 + schunk * 8;
  const _Float16* gA1 = gA0 + (size_t)64 * 512;
  const _Float16* gB0 = B + (size_t)(n_blk + srow) * 512 + schunk * 8;
  const _Float16* gB1 = gB0 + (size_t)64 * 512;
  const int lofs = wave * 512 + lane * 8;

  const int rchunk = (quad ^ ((l16 >> 1) & 3)) * 8;

  f32x4 acc[4][4] = {};

#pragma unroll
  for (int pb = 0; pb < 2; pb++) {
    ASYNC_CP16(gA0 + pb * 32, &As[pb][lofs]);
    ASYNC_CP16(gA1 + pb * 32, &As[pb][lofs + 2048]);
    ASYNC_CP16(gB0 + pb * 32, &Bs[pb][lofs]);
    ASYNC_CP16(gB1 + pb * 32, &Bs[pb][lofs + 2048]);
  }

  int ib = 0;
  for (int k0 = 0; k0 < 256; k0 += 32) {
    if (k0 + 32 < 256)
      asm volatile("s_waitcnt vmcnt(4)\n\ts_barrier" ::: "memory");
    else
      asm volatile("s_waitcnt vmcnt(0)\n\ts_barrier" ::: "memory");
    if (k0 + 64 < 256) {
      int nb = ib + 2;
      if (nb >= 3) nb -= 3;
      const int ko = k0 + 64;
      ASYNC_CP16(gA0 + ko, &As[nb][lofs]);
      ASYNC_CP16(gA1 + ko, &As[nb][lofs + 2048]);
      ASYNC_CP16(gB0 + ko, &Bs[nb][lofs]);
      ASYNC_CP16(gB1 + ko, &Bs[nb][lofs + 2048]);
    }
    half8 af[4], bf[4];
#pragma unroll
    for (int i = 0; i < 4; i++) {
      af[i] = *(const half8*)&As[ib][(wm + i * 16 + l16) * 32 + rchunk];
      bf[i] = *(const half8*)&Bs[ib][(wn + i * 16 + l16) * 32 + rchunk];
    }
#pragma unroll
    for (int i = 0; i < 4; i++)
#pragma unroll
      for (int j = 0; j < 4; j++)
        acc[i][j] =
            __builtin_amdgcn_mfma_f32_16x16x32_f16(af[i], bf[j], acc[i][j], 0, 0, 0);
    ib++;
    if (ib == 3) ib = 0;
  }

  // epilogue: per-wave-column softmax partials + exp-store
#pragma unroll
  for (int j = 0; j < 4; j++) {
    const int n0 = n_blk + wn + j * 16 + l16;
    float mx = acc[0][j][0];
#pragma unroll
    for (int i = 0; i < 4; i++)
#pragma unroll
      for (int r = 0; r < 4; r++) mx = fmaxf(mx, acc[i][j][r]);
    mx = fmaxf(mx, __shfl_xor(mx, 16, 64));
    mx = fmaxf(mx, __shfl_xor(mx, 32, 64));
    float es = 0.f;
#pragma unroll
    for (int i = 0; i < 4; i++) {
      const int m0 = m_blk + wm + i * 16 + quad * 4;
#pragma unroll
      for (int r = 0; r < 4; r++) {
        _Float16 h = (_Float16)__expf(acc[i][j][r] - mx);
        C[(size_t)(m0 + r) * 2048 + n0] = h;
        es += (float)h;
      }
    }
    es += __shfl_xor(es, 16, 64);
    es += __shfl_xor(es, 32, 64);
    if (quad == 0) {
      size_t o =
          ((size_t)blockIdx.z * 32 + blockIdx.y * 2 + (wave & 1)) * 2048 + n0;
      pm[o] = mx;
      ps[o] = es;
    }
  }
}

// ---------------------------------------------------------------------------
// Merge 32 per-64-row partials per column -> fp16 scale[b][32][2048]:
// scale[i][col] = exp(pm_i - M) / S,  S = sum_i ps_i * exp(pm_i - M).
// ---------------------------------------------------------------------------
__global__ __launch_bounds__(256) void colstats2(const float* __restrict__ pm,
                                                 const float* __restrict__ ps,
                                                 _Float16* __restrict__ scl) {
  const int idx = blockIdx.x * 256 + threadIdx.x;  // b*2048 + col
  const int b = idx >> 11, col = idx & 2047;
  const float* pmb = pm + (size_t)b * 32 * 2048 + col;
  const float* psb = ps + (size_t)b * 32 * 2048 + col;
  float pv[32];
  float m = -3.0e38f;
#pragma unroll
  for (int i = 0; i < 32; i++) {
    pv[i] = pmb[(size_t)i * 2048];
    m = fmaxf(m, pv[i]);
  }
  float s = 0.f;
#pragma unroll
  for (int i = 0; i < 32; i++) {
    pv[i] = __expf(pv[i] - m);
    s += psb[(size_t)i * 2048] * pv[i];
  }
  const float inv = 1.0f / s;
  _Float16* so = scl + (size_t)b * 32 * 2048 + col;
#pragma unroll
  for (int i = 0; i < 32; i++) so[(size_t)i * 2048] = (_Float16)(pv[i] * inv);
}

// ---------------------------------------------------------------------------
// Stage-D: out[m][c] = sum_k (P[m][k]*scale[m>>6,k]) * V[c][k].
// ROUND-6 (PROVEN, unchanged): phase-split schedule (T3+T4+T5 port).
// 512 thr, tile 128m x 256c, wave 64x64 (4x4), grid 32/batch x 8 = 256 =
// 1 block/CU, batch-per-XCD.  BK64 as 2 sub-phases; B via 4 cp16 issued in
// ph0; A reg+mulw(scale)+ds_write, glob prefetch dist 2 issued in ph1;
// counted vmcnt(4) once per K-tile.  Measured: 47us, MfmaUtil 27.
// ---------------------------------------------------------------------------
__global__ __launch_bounds__(512) void gemm_av(const _Float16* __restrict__ P,
                                               const _Float16* __restrict__ V,
                                               const _Float16* __restrict__ scl,
                                               float* __restrict__ C,
                                               int cbatch) {
  int lin = blockIdx.x, z, idx;
  if (cbatch == 8) {
    z = lin & 7;      // batch = XCD
    idx = lin >> 3;   // 0..31
  } else {
    z = lin >> 5;
    idx = lin & 31;
  }
  const int n_blk = (idx & 1) * 256;   // c-dim (2 blocks)
  const int m_blk = (idx >> 1) * 128;  // m-dim (16 blocks)
  P += (size_t)z * 2048 * 2048;
  V += (size_t)z * 512 * 2048;
  scl += (size_t)z * 32 * 2048;
  C += (size_t)z * 2048 * 512;

  __shared__ __align__(16) _Float16 Asv[2][2][4096];  // [buf][kk][128r x 32k]
  __shared__ __align__(16) _Float16 Bsv[2][2][8192];  // [buf][kk][256r x 32k]

  const int t = threadIdx.x;
  const int lane = t & 63, wave = t >> 6;
  const int quad = lane >> 4, l16 = lane & 15;
  const int wm = (wave & 1) * 64, wn = (wave >> 1) * 64;

  const int arow = t >> 2;                       // 0..127
  const int aslot = t & 3;
  const int adc = aslot ^ ((arow >> 1) & 3);     // global-side XOR swizzle
  const _Float16* gA = P + (size_t)(m_blk + arow) * 2048 + adc * 8;
  const _Float16* gS = scl + (size_t)((m_blk + arow) >> 6) * 2048 + adc * 8;
  const int awofs = arow * 32 + aslot * 8;

  const int brow0 = (wave << 4) + (lane >> 2);          // 0..127
  const int bdc = (lane & 3) ^ ((brow0 >> 1) & 3);
  const _Float16* gB = V + (size_t)(n_blk + brow0) * 2048 + bdc * 8;
  const int bwofs = wave << 9;  // wave*512 halves (HW adds lane*16B)

  const int rchunk = (quad ^ ((l16 >> 1) & 3)) * 8;

  f32x4 acc[4][4] = {};

  // ---- prologue: B tile0 (4 cp16); A tile0 staged; A tile1 in regs ----
  ASYNC_CP16(gB, &Bsv[0][0][bwofs]);
  ASYNC_CP16(gB + (size_t)128 * 2048, &Bsv[0][0][4096 + bwofs]);
  ASYNC_CP16(gB + 32, &Bsv[0][1][bwofs]);
  ASYNC_CP16(gB + (size_t)128 * 2048 + 32, &Bsv[0][1][4096 + bwofs]);
  {
    half8 a00 = *(const half8*)(gA);
    half8 s00 = *(const half8*)(gS);
    half8 a01 = *(const half8*)(gA + 32);
    half8 s01 = *(const half8*)(gS + 32);
    *(half8*)&Asv[0][0][awofs] = mulw(a00, s00);
    *(half8*)&Asv[0][1][awofs] = mulw(a01, s01);
  }
  half8 pA0 = *(const half8*)(gA + 64);
  half8 pS0 = *(const half8*)(gS + 64);
  half8 pA1 = *(const half8*)(gA + 96);
  half8 pS1 = *(const half8*)(gS + 96);
  asm volatile("s_waitcnt vmcnt(4) lgkmcnt(0)\n\ts_barrier" ::: "memory");
  __builtin_amdgcn_sched_barrier(0);

  for (int T = 0; T < 32; T++) {
    const int c = T & 1, n = c ^ 1;
    const int k1 = (T + 1) * 64;  // B stage k-base
    const int k2 = (T + 2) * 64;  // A glob prefetch k-base
    // ---------------- phase 0 ----------------
    half8 af[4], bf[4];
#pragma unroll
    for (int i = 0; i < 4; i++) {
      af[i] = *(const half8*)&Asv[c][0][(wm + i * 16 + l16) * 32 + rchunk];
      bf[i] = *(const half8*)&Bsv[c][0][(wn + i * 16 + l16) * 32 + rchunk];
    }
    if (T < 31) {
      ASYNC_CP16(gB + k1, &Bsv[n][0][bwofs]);
      ASYNC_CP16(gB + (size_t)128 * 2048 + k1, &Bsv[n][0][4096 + bwofs]);
      ASYNC_CP16(gB + k1 + 32, &Bsv[n][1][bwofs]);
      ASYNC_CP16(gB + (size_t)128 * 2048 + k1 + 32, &Bsv[n][1][4096 + bwofs]);
      *(half8*)&Asv[n][0][awofs] = mulw(pA0, pS0);
    }
    asm volatile("s_barrier" ::: "memory");
    __builtin_amdgcn_sched_barrier(0);
    __builtin_amdgcn_s_setprio(1);
#pragma unroll
    for (int i = 0; i < 4; i++)
#pragma unroll
      for (int j = 0; j < 4; j++)
        acc[i][j] =
            __builtin_amdgcn_mfma_f32_16x16x32_f16(af[i], bf[j], acc[i][j], 0, 0, 0);
    __builtin_amdgcn_s_setprio(0);
    asm volatile("s_barrier" ::: "memory");
    __builtin_amdgcn_sched_barrier(0);
    // ---------------- phase 1 ----------------
    half8 af2[4], bf2[4];
#pragma unroll
    for (int i = 0; i < 4; i++) {
      af2[i] = *(const half8*)&Asv[c][1][(wm + i * 16 + l16) * 32 + rchunk];
      bf2[i] = *(const half8*)&Bsv[c][1][(wn + i * 16 + l16) * 32 + rchunk];
    }
    half8 fA0, fS0, fA1, fS1;
    if (T < 30) {
      fA0 = *(const half8*)(gA + k2);
      fS0 = *(const half8*)(gS + k2);
      fA1 = *(const half8*)(gA + k2 + 32);
      fS1 = *(const half8*)(gS + k2 + 32);
    }
    if (T < 31) *(half8*)&Asv[n][1][awofs] = mulw(pA1, pS1);
    if (T < 30) {
      pA0 = fA0;
      pS0 = fS0;
      pA1 = fA1;
      pS1 = fS1;
    }
    if (T < 30)
      asm volatile("s_waitcnt vmcnt(4) lgkmcnt(0)\n\ts_barrier" ::: "memory");
    else
      asm volatile("s_waitcnt vmcnt(0) lgkmcnt(0)\n\ts_barrier" ::: "memory");
    __builtin_amdgcn_sched_barrier(0);
    __builtin_amdgcn_s_setprio(1);
#pragma unroll
    for (int i = 0; i < 4; i++)
#pragma unroll
      for (int j = 0; j < 4; j++)
        acc[i][j] =
            __builtin_amdgcn_mfma_f32_16x16x32_f16(af2[i], bf2[j], acc[i][j], 0, 0, 0);
    __builtin_amdgcn_s_setprio(0);
    asm volatile("s_barrier" ::: "memory");
    __builtin_amdgcn_sched_barrier(0);
  }

  // epilogue: natural fp32 store C[m][c]
#pragma unroll
  for (int i = 0; i < 4; i++) {
    const int m0 = m_blk + wm + i * 16 + quad * 4;
#pragma unroll
    for (int j = 0; j < 4; j++) {
      const int n0 = n_blk + wn + j * 16 + l16;
#pragma unroll
      for (int r = 0; r < 4; r++) C[(size_t)(m0 + r) * 512 + n0] = acc[i][j][r];
    }
  }
}

// ---------------------------------------------------------------------------
extern "C" void kernel_launch(void* const* d_in, const int* in_sizes, int n_in,
                              void* d_out, int out_size, void* d_ws,
                              size_t ws_size, hipStream_t stream) {
  const float* x = (const float*)d_in[0];
  const float* Wq = (const float*)d_in[1];
  const float* Wk = (const float*)d_in[2];
  const float* Wv = (const float*)d_in[3];
  float* out = (float*)d_out;

  char* p = (char*)d_ws;
  auto alloc = [&](size_t bytes) -> char* {
    char* r = p;
    p += (bytes + 255) & ~(size_t)255;
    return r;
  };
  const size_t NB = 8, N = 2048, CIN = 512, CO = 512;
  _Float16* Wb = (_Float16*)alloc(1024 * 512 * sizeof(_Float16));
  _Float16* xT = (_Float16*)alloc(NB * N * CIN * sizeof(_Float16));
  _Float16* qkT = (_Float16*)alloc(NB * N * 512 * sizeof(_Float16));  // [n][q|k]
  _Float16* v = (_Float16*)alloc(NB * CO * N * sizeof(_Float16));     // [c][n]
  size_t base_used = (size_t)(p - (char*)d_ws);

  // per-batch bytes for the sim chain: fp16 P + partials + scale + slack
  const size_t per_b =
      (size_t)N * N * 2 + 2 * 32 * N * 4 + 32 * N * 2 + 8192;
  int cb = 8;
  while (cb > 1 && base_used + (size_t)cb * per_b > ws_size) cb >>= 1;
  _Float16* simH = (_Float16*)alloc((size_t)cb * N * N * 2);
  float* pm = (float*)alloc((size_t)cb * 32 * N * 4);
  float* ps = (float*)alloc((size_t)cb * 32 * N * 4);
  _Float16* scl = (_Float16*)alloc((size_t)cb * 32 * N * 2);

  // 1) weight convert + x transpose-convert
  conv_w<<<dim3(1024 * 512 / 256), 256, 0, stream>>>(Wq, Wk, Wv, Wb);
  conv_xT<<<dim3(64, 16, 8), 256, 0, stream>>>(x, xT);

  // 2) merged projections (q,k,v in one pass over xT), phase-split:
  //    rows<512 -> qkT[n][o] transposed; rows>=512 -> v[c][n] natural
  gemm_proj<8><<<dim3(8, 8, 8), 512, 0, stream>>>(
      Wb, xT, qkT, v, 512, 512, 512, 2048, 0, (long)(N * CIN),
      (long)(N * 512));

  // 3) per-chunk: simH = fp16(exp(qT.kT^T - mx_wave)) + partials; merge ->
  //    fp16 scale; stage-D GEMM applies scale during A-staging -> out
  for (int b0 = 0; b0 < 8; b0 += cb) {
    const _Float16* qT = qkT + (size_t)b0 * N * 512;        // [m][c], lda 512
    const _Float16* kT = qkT + (size_t)b0 * N * 512 + 256;  // [k][c], ldb 512
    gemm_sim<<<dim3(16, 16, cb), 256, 0, stream>>>(
        qT, kT, simH, (long)(N * 512), (long)(N * 512), (long)(N * N), pm, ps);
    colstats2<<<dim3(cb * 8), 256, 0, stream>>>(pm, ps, scl);
    gemm_av<<<dim3(32 * cb), 512, 0, stream>>>(
        simH, v + (size_t)b0 * CO * N, scl, out + (size_t)b0 * N * CO, cb);
  }
}